// Round 8
// baseline (606.062 us; speedup 1.0000x reference)
//
#include <hip/hip_runtime.h>
#include <stdint.h>

#define GAS __attribute__((address_space(1)))
#define LAS __attribute__((address_space(3)))

typedef __attribute__((ext_vector_type(8))) short short8;
typedef __attribute__((ext_vector_type(4))) float float4v;
typedef __attribute__((ext_vector_type(16))) float float16v;
typedef __attribute__((ext_vector_type(4))) unsigned int uint4v;

__device__ __forceinline__ unsigned short f2bf(float f) {
  union { float f; unsigned int u; } v; v.f = f;
  unsigned int r = v.u + 0x7fffu + ((v.u >> 16) & 1u);
  return (unsigned short)(r >> 16);
}

__device__ __forceinline__ void async_g2l16(const void* g, void* l) {
  __builtin_amdgcn_global_load_lds((const GAS unsigned int*)g,
                                   (LAS unsigned int*)l, 16, 0, 0);
}

__device__ __forceinline__ void vmem_drain() {
  asm volatile("s_waitcnt vmcnt(0)" ::: "memory");
}

// ---- Kernel A: normalize y -> bf16 fragment-major for 32x32x16 B-operand --
// Fragment (og,kc) is 1KB (512 shorts): lane = half*32 + (o&31) holds
// o = og*32 + (o&31), c = kc*16 + half*8 + j   (B map: col=lane&31,
// k=(lane>>5)*8+j — generalization verified by the 16x16x32 kernel).
__global__ void knorm_y(const float* __restrict__ y, unsigned short* __restrict__ y_t2) {
  int o = blockIdx.x;
  int tid = threadIdx.x;
  const float* yo = y + o * 16384;
  float s = 0.f;
  for (int idx = tid; idx < 16384; idx += 256) { float v = yo[idx]; s += v * v; }
  for (int off = 32; off; off >>= 1) s += __shfl_down(s, off, 64);
  __shared__ float red[4];
  if ((tid & 63) == 0) red[tid >> 6] = s;
  __syncthreads();
  float rn = 1.0f / sqrtf(red[0] + red[1] + red[2] + red[3]);
  int og = o >> 5, ol = o & 31;
  for (int idx = tid; idx < 16384; idx += 256) {
    int c = idx >> 8, dy = (idx >> 4) & 15, dx = idx & 15;
    int t = dy * 16 + dx;
    int kc = c >> 4, half = (c >> 3) & 1, j = c & 7;
    size_t dst = (size_t)t * 4096 + (size_t)(og * 4 + kc) * 512 + (half * 32 + ol) * 8 + j;
    y_t2[dst] = f2bf(yo[idx] * rn);
  }
}

// ------- Kernel B: x (NCHW f32) -> x_t bf16 [n][h][w][c] swizzled, + s -----
__global__ void ktrans_x(const float* __restrict__ x, unsigned short* __restrict__ x_t,
                         float* __restrict__ s) {
  int h = blockIdx.x, n = blockIdx.y;
  int tid = threadIdx.x;
  __shared__ __align__(16) unsigned short tb[8192];
  __shared__ float sb[256];
  const float* xb = x + ((size_t)n * 64) * 16384 + h * 128;
  int w = tid & 127, half = tid >> 7;
  float acc = 0.f;
#pragma unroll
  for (int cs = 0; cs < 4; ++cs) {
    short8 tmp;
#pragma unroll
    for (int j = 0; j < 8; ++j) {
      int c = half * 32 + cs * 8 + j;
      float v = xb[(size_t)c * 16384 + w];
      tmp[j] = (short)f2bf(v);
      acc += v * v;
    }
    int chunk = (half * 4 + cs) ^ (w & 7);
    *(short8*)(tb + w * 64 + chunk * 8) = tmp;
  }
  sb[tid] = acc;
  __syncthreads();
  uint4v* dst = (uint4v*)(x_t + ((size_t)(n * 128 + h)) * 8192);
  const uint4v* src = (const uint4v*)tb;
  for (int idx = tid; idx < 1024; idx += 256) dst[idx] = src[idx];
  if (tid < 128) s[((size_t)(n * 128 + h)) * 128 + tid] = sb[tid] + sb[tid + 128];
}

// ---------------- Kernel D: separable 16x16 box sum of s -> 1/sqrt --------
__global__ void knorm_x(const float* __restrict__ s, float* __restrict__ invn) {
  int i = blockIdx.x, n = blockIdx.y;
  int tid = threadIdx.x;  // 128
  __shared__ float colsum[128];
  const float* sp = s + ((size_t)(n * 128 + i)) * 128;
  float a = 0.f;
#pragma unroll
  for (int dy = 0; dy < 16; ++dy) a += sp[dy * 128 + tid];
  colsum[tid] = a;
  __syncthreads();
  if (tid < 113) {
    float acc = 0.f;
#pragma unroll
    for (int dx = 0; dx < 16; ++dx) acc += colsum[tid + dx];
    invn[((size_t)n * 113 + i) * 113 + tid] = 1.0f / sqrtf(acc);
  }
}

// ---------------- Kernel E: main implicit-GEMM conv -----------------------
// R7: REVERT R6 (L2 thrash + serialized stage). Base = R4's 395us kernel
// (XCD swizzle, depth-1 B ping-pong, vmcnt(4), sched_barrier-pinned stageA).
// SINGLE change: MFMA shape 16x16x32 -> 32x32x16. Same FLOPs in 8 MFMA/
// wave/t instead of 16 (4096 vs 3378 FLOP/issue-cyc; ceiling 2382 vs 2075
// TF). A-LDS reads/wave/t unchanged (8x b128), B loads unchanged (4x 16B).
// Wave tile now 64j x 32o: wrow = j-half, wcol = o-half. C/D map (m74/m101):
// o = lane&31, j = (reg&3) + 8*(reg>>2) + 4*(lane>>5) -> reg quads are 4
// consecutive j -> direct float4 epilogue (R3/R6-verified pattern).
__launch_bounds__(256, 3)
__global__ void kconv(const unsigned short* __restrict__ x_t,
                      const unsigned short* __restrict__ y_t2,
                      const float* __restrict__ invn,
                      float* __restrict__ out) {
  // XCD-chunked swizzle: hw round-robins linear wg id across 8 XCDs.
  int lin = blockIdx.y * 113 + blockIdx.x;
  int wg = (lin & 7) * 226 + (lin >> 3);   // bijective: 1808 = 8*226
  int i = wg % 113;
  int n = wg / 113;
  int tid = threadIdx.x;
  int lane = tid & 63, wave = tid >> 6;
  int lane31 = lane & 31, l5 = lane >> 5;
  int wrow = wave >> 1, wcol = wave & 1;

  __shared__ __align__(16) char smem[32768];
  char* const A0 = smem;
  char* const A1 = smem + 16384;

  const char* xrow0 = (const char*)(x_t + ((size_t)(n * 128 + i)) * 8192);

  auto stageA = [&](int dy, char* buf) {
    const char* src = xrow0 + (size_t)dy * 16384;
#pragma unroll
    for (int it = 0; it < 4; ++it) {
      int chunk = it * 256 + wave * 64;  // wave-uniform LDS base
      async_g2l16(src + (chunk + lane) * 16, buf + chunk * 16);
    }
  };

  // B fragments: og = wcol (o-half), kc = 0..3 (16-c chunks of the t's 64 c).
  const short8* ybase = (const short8*)y_t2 + (size_t)wcol * 256 + lane;
  auto loadB = [&](int t, short8 bf[4]) {
    const short8* p = ybase + (size_t)t * 512;  // 512 short8 = 4096 shorts per t
    bf[0] = p[0];
    bf[1] = p[64];
    bf[2] = p[128];
    bf[3] = p[192];
  };

  float16v acc[2];
  acc[0] = 0.f;
  acc[1] = 0.f;

  int abase[2];
#pragma unroll
  for (int mt = 0; mt < 2; ++mt)
    abase[mt] = (wrow * 64 + mt * 32 + lane31) * 128;

  short8 b0[4], b1[4];
  stageA(0, A0);
  loadB(0, b0);
  vmem_drain();
  __syncthreads();

#pragma unroll 1
  for (int dy = 0; dy < 16; ++dy) {
    char* Ab = (dy & 1) ? A1 : A0;
    if (dy < 15) {
      __builtin_amdgcn_sched_barrier(0);
      stageA(dy + 1, (dy & 1) ? A0 : A1);
      __builtin_amdgcn_sched_barrier(0);
    }
#pragma unroll
    for (int dx = 0; dx < 16; ++dx) {
      int t = dy * 16 + dx;
      // compile-time ping-pong after unroll: no register copies
      short8(&bc)[4] = (dx & 1) ? b1 : b0;
      short8(&bn)[4] = (dx & 1) ? b0 : b1;
      if (t < 255) loadB(t + 1, bn);
      int xr = (lane31 + dx) & 7;
#pragma unroll
      for (int kc = 0; kc < 4; ++kc) {
#pragma unroll
        for (int mt = 0; mt < 2; ++mt) {
          // A frag: row = j = wrow*64+mt*32+lane31 (+dx via dx*128);
          // c-chunk index (c/8) = kc*2 + l5, stored XOR (w&7).
          int aoff = dx * 128 + (((kc * 2 + l5) ^ xr) << 4);
          short8 a = *(const short8*)(Ab + abase[mt] + aoff);
          acc[mt] = __builtin_amdgcn_mfma_f32_32x32x16_bf16(a, bc[kc], acc[mt], 0, 0, 0);
        }
      }
    }
    // Relaxed drain: stageA's 4 LDS-DMA are older than the 4 newest VMEM
    // ops (dx=15's loadB) -> vmcnt(4) guarantees they landed while keeping
    // the B prefetch in flight across the barrier.
    asm volatile("s_waitcnt vmcnt(4)" ::: "memory");
    __syncthreads();
  }

  // Epilogue: direct stores. o = wcol*32 + lane31;
  // j = wrow*64 + mt*32 + rg*8 + l5*4 + k  (reg = rg*4+k, k=0..3).
  const float* ivp = invn + ((size_t)n * 113 + i) * 113;
  float* op = out + (size_t)n * 64 * 12769 + (size_t)i * 113;
  int o = wcol * 32 + lane31;
#pragma unroll
  for (int mt = 0; mt < 2; ++mt) {
#pragma unroll
    for (int rg = 0; rg < 4; ++rg) {
      int j0 = wrow * 64 + mt * 32 + rg * 8 + l5 * 4;
      if (j0 <= 108) {
        float4v iv = *(const float4v*)(ivp + j0);
        float4v r;
        r[0] = fmaxf(acc[mt][rg * 4 + 0] * iv[0], 0.f);
        r[1] = fmaxf(acc[mt][rg * 4 + 1] * iv[1], 0.f);
        r[2] = fmaxf(acc[mt][rg * 4 + 2] * iv[2], 0.f);
        r[3] = fmaxf(acc[mt][rg * 4 + 3] * iv[3], 0.f);
        *(float4v*)(op + (size_t)o * 12769 + j0) = r;
      } else if (j0 == 112) {
        op[(size_t)o * 12769 + 112] = fmaxf(acc[mt][rg * 4] * ivp[112], 0.f);
      }
    }
  }
}

extern "C" void kernel_launch(void* const* d_in, const int* in_sizes, int n_in,
                              void* d_out, int out_size, void* d_ws, size_t ws_size,
                              hipStream_t stream) {
  const float* x = (const float*)d_in[0];
  const float* y = (const float*)d_in[1];
  float* out = (float*)d_out;
  char* ws = (char*)d_ws;
  unsigned short* x_t = (unsigned short*)ws;                 // 33,554,432 B
  unsigned short* y_t2 = (unsigned short*)(ws + 33554432);   //  2,097,152 B
  float* s = (float*)(ws + 35651584);                        //  1,048,576 B
  float* invn = (float*)(ws + 36700160);                     //    817,216 B

  hipLaunchKernelGGL(knorm_y, dim3(64), dim3(256), 0, stream, y, y_t2);
  hipLaunchKernelGGL(ktrans_x, dim3(128, 16), dim3(256), 0, stream, x, x_t, s);
  hipLaunchKernelGGL(knorm_x, dim3(113, 16), dim3(128), 0, stream, s, invn);
  hipLaunchKernelGGL(kconv, dim3(113, 16), dim3(256), 0, stream, x_t, y_t2, invn, out);
}

// Round 9
// 595.660 us; speedup vs baseline: 1.0175x; 1.0175x over previous
//
#include <hip/hip_runtime.h>
#include <stdint.h>

#define GAS __attribute__((address_space(1)))
#define LAS __attribute__((address_space(3)))

typedef __attribute__((ext_vector_type(8))) short short8;
typedef __attribute__((ext_vector_type(4))) float float4v;
typedef __attribute__((ext_vector_type(16))) float float16v;
typedef __attribute__((ext_vector_type(4))) unsigned int uint4v;

__device__ __forceinline__ unsigned short f2bf(float f) {
  union { float f; unsigned int u; } v; v.f = f;
  unsigned int r = v.u + 0x7fffu + ((v.u >> 16) & 1u);
  return (unsigned short)(r >> 16);
}

__device__ __forceinline__ void async_g2l16(const void* g, void* l) {
  __builtin_amdgcn_global_load_lds((const GAS unsigned int*)g,
                                   (LAS unsigned int*)l, 16, 0, 0);
}

__device__ __forceinline__ void vmem_drain() {
  asm volatile("s_waitcnt vmcnt(0)" ::: "memory");
}

// ---- Kernel A: normalize y -> bf16 fragment-major for 32x32x16 B-operand --
// Fragment (og,kc) is 1KB (512 shorts): lane = half*32 + (o&31) holds
// o = og*32 + (o&31), c = kc*16 + half*8 + j   (B map: col=lane&31,
// k=(lane>>5)*8+j — generalization verified by the 16x16x32 kernel).
__global__ void knorm_y(const float* __restrict__ y, unsigned short* __restrict__ y_t2) {
  int o = blockIdx.x;
  int tid = threadIdx.x;
  const float* yo = y + o * 16384;
  float s = 0.f;
  for (int idx = tid; idx < 16384; idx += 256) { float v = yo[idx]; s += v * v; }
  for (int off = 32; off; off >>= 1) s += __shfl_down(s, off, 64);
  __shared__ float red[4];
  if ((tid & 63) == 0) red[tid >> 6] = s;
  __syncthreads();
  float rn = 1.0f / sqrtf(red[0] + red[1] + red[2] + red[3]);
  int og = o >> 5, ol = o & 31;
  for (int idx = tid; idx < 16384; idx += 256) {
    int c = idx >> 8, dy = (idx >> 4) & 15, dx = idx & 15;
    int t = dy * 16 + dx;
    int kc = c >> 4, half = (c >> 3) & 1, j = c & 7;
    size_t dst = (size_t)t * 4096 + (size_t)(og * 4 + kc) * 512 + (half * 32 + ol) * 8 + j;
    y_t2[dst] = f2bf(yo[idx] * rn);
  }
}

// ------- Kernel B: x (NCHW f32) -> x_t bf16 [n][h][w][c] swizzled, + s -----
// R8: swizzle widened to 5 row bits: chunk = cc ^ (w&7) ^ ((w>>3)&3).
// The old 3-bit XOR gave 4-way bank conflicts for 32-row (32x32 MFMA)
// A-reads (lanes w, w+8, w+16, w+24 alias). Now any 32 contiguous rows map
// each chunk slot to <=2 lanes (the pattern that measured 0 conflicts).
__global__ void ktrans_x(const float* __restrict__ x, unsigned short* __restrict__ x_t,
                         float* __restrict__ s) {
  int h = blockIdx.x, n = blockIdx.y;
  int tid = threadIdx.x;
  __shared__ __align__(16) unsigned short tb[8192];
  __shared__ float sb[256];
  const float* xb = x + ((size_t)n * 64) * 16384 + h * 128;
  int w = tid & 127, half = tid >> 7;
  float acc = 0.f;
#pragma unroll
  for (int cs = 0; cs < 4; ++cs) {
    short8 tmp;
#pragma unroll
    for (int j = 0; j < 8; ++j) {
      int c = half * 32 + cs * 8 + j;
      float v = xb[(size_t)c * 16384 + w];
      tmp[j] = (short)f2bf(v);
      acc += v * v;
    }
    int chunk = (half * 4 + cs) ^ (w & 7) ^ ((w >> 3) & 3);
    *(short8*)(tb + w * 64 + chunk * 8) = tmp;
  }
  sb[tid] = acc;
  __syncthreads();
  uint4v* dst = (uint4v*)(x_t + ((size_t)(n * 128 + h)) * 8192);
  const uint4v* src = (const uint4v*)tb;
  for (int idx = tid; idx < 1024; idx += 256) dst[idx] = src[idx];
  if (tid < 128) s[((size_t)(n * 128 + h)) * 128 + tid] = sb[tid] + sb[tid + 128];
}

// ---------------- Kernel D: separable 16x16 box sum of s -> 1/sqrt --------
__global__ void knorm_x(const float* __restrict__ s, float* __restrict__ invn) {
  int i = blockIdx.x, n = blockIdx.y;
  int tid = threadIdx.x;  // 128
  __shared__ float colsum[128];
  const float* sp = s + ((size_t)(n * 128 + i)) * 128;
  float a = 0.f;
#pragma unroll
  for (int dy = 0; dy < 16; ++dy) a += sp[dy * 128 + tid];
  colsum[tid] = a;
  __syncthreads();
  if (tid < 113) {
    float acc = 0.f;
#pragma unroll
    for (int dx = 0; dx < 16; ++dx) acc += colsum[tid + dx];
    invn[((size_t)n * 113 + i) * 113 + tid] = 1.0f / sqrtf(acc);
  }
}

// ---------------- Kernel E: main implicit-GEMM conv -----------------------
// R8: keep R7's 32x32x16 shape (8 MFMA/wave/t vs 16; 4096 vs 3378 FLOP/
// issue-cyc), FIX its measured 4-way LDS bank conflict (5.9e7): the A-read
// spans 32 rows but the swizzle XOR space was 3 bits. Widened swizzle
// chunk = cc ^ (row&7) ^ ((row>>3)&3) makes same-(row&7) lanes hit distinct
// 16B slots; any 16 contiguous rows = 2 lanes/slot = conflict-free pattern.
// Base otherwise = R4's 395us structure (XCD swizzle, depth-1 B ping-pong,
// vmcnt(4), sched_barrier-pinned stageA).
__launch_bounds__(256, 3)
__global__ void kconv(const unsigned short* __restrict__ x_t,
                      const unsigned short* __restrict__ y_t2,
                      const float* __restrict__ invn,
                      float* __restrict__ out) {
  // XCD-chunked swizzle: hw round-robins linear wg id across 8 XCDs.
  int lin = blockIdx.y * 113 + blockIdx.x;
  int wg = (lin & 7) * 226 + (lin >> 3);   // bijective: 1808 = 8*226
  int i = wg % 113;
  int n = wg / 113;
  int tid = threadIdx.x;
  int lane = tid & 63, wave = tid >> 6;
  int lane31 = lane & 31, l5 = lane >> 5;
  int wrow = wave >> 1, wcol = wave & 1;

  __shared__ __align__(16) char smem[32768];
  char* const A0 = smem;
  char* const A1 = smem + 16384;

  const char* xrow0 = (const char*)(x_t + ((size_t)(n * 128 + i)) * 8192);

  auto stageA = [&](int dy, char* buf) {
    const char* src = xrow0 + (size_t)dy * 16384;
#pragma unroll
    for (int it = 0; it < 4; ++it) {
      int chunk = it * 256 + wave * 64;  // wave-uniform LDS base
      async_g2l16(src + (chunk + lane) * 16, buf + chunk * 16);
    }
  };

  // B fragments: og = wcol (o-half), kc = 0..3 (16-c chunks of the t's 64 c).
  const short8* ybase = (const short8*)y_t2 + (size_t)wcol * 256 + lane;
  auto loadB = [&](int t, short8 bf[4]) {
    const short8* p = ybase + (size_t)t * 512;  // 512 short8 = 4096 shorts per t
    bf[0] = p[0];
    bf[1] = p[64];
    bf[2] = p[128];
    bf[3] = p[192];
  };

  float16v acc[2];
  acc[0] = 0.f;
  acc[1] = 0.f;

  int abase[2];
#pragma unroll
  for (int mt = 0; mt < 2; ++mt)
    abase[mt] = (wrow * 64 + mt * 32 + lane31) * 128;

  short8 b0[4], b1[4];
  stageA(0, A0);
  loadB(0, b0);
  vmem_drain();
  __syncthreads();

#pragma unroll 1
  for (int dy = 0; dy < 16; ++dy) {
    char* Ab = (dy & 1) ? A1 : A0;
    if (dy < 15) {
      __builtin_amdgcn_sched_barrier(0);
      stageA(dy + 1, (dy & 1) ? A0 : A1);
      __builtin_amdgcn_sched_barrier(0);
    }
#pragma unroll
    for (int dx = 0; dx < 16; ++dx) {
      int t = dy * 16 + dx;
      // compile-time ping-pong after unroll: no register copies
      short8(&bc)[4] = (dx & 1) ? b1 : b0;
      short8(&bn)[4] = (dx & 1) ? b0 : b1;
      if (t < 255) loadB(t + 1, bn);
      // row = wrow*64 + mt*32 + lane31 + dx; base terms are 0 mod 32, so
      // row&7 and (row>>3)&3 depend only on lane31+dx.
      int rl = lane31 + dx;
      int xr = rl & 7;
      int r3 = (rl >> 3) & 3;
#pragma unroll
      for (int kc = 0; kc < 4; ++kc) {
#pragma unroll
        for (int mt = 0; mt < 2; ++mt) {
          // physical chunk = cc ^ (row&7) ^ ((row>>3)&3), cc = kc*2+l5
          int aoff = dx * 128 + ((((kc * 2 + l5) ^ xr ^ r3)) << 4);
          short8 a = *(const short8*)(Ab + abase[mt] + aoff);
          acc[mt] = __builtin_amdgcn_mfma_f32_32x32x16_bf16(a, bc[kc], acc[mt], 0, 0, 0);
        }
      }
    }
    // Relaxed drain: stageA's 4 LDS-DMA are older than the 4 newest VMEM
    // ops (dx=15's loadB) -> vmcnt(4) guarantees they landed while keeping
    // the B prefetch in flight across the barrier.
    asm volatile("s_waitcnt vmcnt(4)" ::: "memory");
    __syncthreads();
  }

  // Epilogue: direct stores. o = wcol*32 + lane31;
  // j = wrow*64 + mt*32 + rg*8 + l5*4 + k  (reg = rg*4+k, k=0..3).
  const float* ivp = invn + ((size_t)n * 113 + i) * 113;
  float* op = out + (size_t)n * 64 * 12769 + (size_t)i * 113;
  int o = wcol * 32 + lane31;
#pragma unroll
  for (int mt = 0; mt < 2; ++mt) {
#pragma unroll
    for (int rg = 0; rg < 4; ++rg) {
      int j0 = wrow * 64 + mt * 32 + rg * 8 + l5 * 4;
      if (j0 <= 108) {
        float4v iv = *(const float4v*)(ivp + j0);
        float4v r;
        r[0] = fmaxf(acc[mt][rg * 4 + 0] * iv[0], 0.f);
        r[1] = fmaxf(acc[mt][rg * 4 + 1] * iv[1], 0.f);
        r[2] = fmaxf(acc[mt][rg * 4 + 2] * iv[2], 0.f);
        r[3] = fmaxf(acc[mt][rg * 4 + 3] * iv[3], 0.f);
        *(float4v*)(op + (size_t)o * 12769 + j0) = r;
      } else if (j0 == 112) {
        op[(size_t)o * 12769 + 112] = fmaxf(acc[mt][rg * 4] * ivp[112], 0.f);
      }
    }
  }
}

extern "C" void kernel_launch(void* const* d_in, const int* in_sizes, int n_in,
                              void* d_out, int out_size, void* d_ws, size_t ws_size,
                              hipStream_t stream) {
  const float* x = (const float*)d_in[0];
  const float* y = (const float*)d_in[1];
  float* out = (float*)d_out;
  char* ws = (char*)d_ws;
  unsigned short* x_t = (unsigned short*)ws;                 // 33,554,432 B
  unsigned short* y_t2 = (unsigned short*)(ws + 33554432);   //  2,097,152 B
  float* s = (float*)(ws + 35651584);                        //  1,048,576 B
  float* invn = (float*)(ws + 36700160);                     //    817,216 B

  hipLaunchKernelGGL(knorm_y, dim3(64), dim3(256), 0, stream, y, y_t2);
  hipLaunchKernelGGL(ktrans_x, dim3(128, 16), dim3(256), 0, stream, x, x_t, s);
  hipLaunchKernelGGL(knorm_x, dim3(113, 16), dim3(128), 0, stream, s, invn);
  hipLaunchKernelGGL(kconv, dim3(113, 16), dim3(256), 0, stream, x_t, y_t2, invn, out);
}